// Round 16
// baseline (1531.445 us; speedup 1.0000x reference)
//
#include <hip/hip_runtime.h>
#include <math.h>

#define M_D   120
#define MOD_T 201
#define TABLE_MASK 0xFFFFFu
#define INV_S 0.25819888974716115f   // 1/sqrt(15)

// ws float-region: S11[201*8] @0 ; TV'[201*128] @1608 ; TQK'[201*128] (u32) @27336
// frag dwords @53248 (byte 212992, 131072 B) ; TVh f16 @byte 344064 (51456 B)
// dyn16 @ 1 MB ; feat after dyn16
#define WS_TV   1608
#define WS_TQK  27336
#define WS_QF   53248
#define WS_TVH_BYTE 344064ull
#define WS_DYN16_BYTE (1ull << 20)

typedef float    f32x4 __attribute__((ext_vector_type(4)));
typedef uint32_t u32x4 __attribute__((ext_vector_type(4)));
typedef __fp16   f16x2v __attribute__((ext_vector_type(2)));
typedef __fp16   f16x4v __attribute__((ext_vector_type(4)));
typedef __fp16   f16x8 __attribute__((ext_vector_type(8)));

union PK2 { f16x2v h; uint32_t u; };
union BFrag { f16x8 v; f16x2v h2[4]; uint32_t u[4]; };

// ---------- precompute padded time-token tables (+ f16 TV copy) ----------
__global__ void precomp_time(const float* __restrict__ temb,
                             const float* __restrict__ Wq, const float* __restrict__ bq,
                             const float* __restrict__ Wk, const float* __restrict__ bk,
                             const float* __restrict__ Wv, const float* __restrict__ bv,
                             float* __restrict__ ws) {
  const int t = blockIdx.x, np = threadIdx.x;
  const int h = np >> 4, m = np & 15;
  const bool valid = (m < 15);
  const int col = h * 15 + m;
  __shared__ float lq[128], lk[128];
  float q = 0.f, k = 0.f, v = 0.f;
  if (valid) {
    q = bq[col]; k = bk[col]; v = bv[col];
    const float* te = temb + t * M_D;
    for (int i = 0; i < M_D; ++i) {
      float x = te[i];
      q = fmaf(x, Wq[i * M_D + col], q);
      k = fmaf(x, Wk[i * M_D + col], k);
      v = fmaf(x, Wv[i * M_D + col], v);
    }
  }
  lq[np] = q; lk[np] = k;
  ws[WS_TV + t * 128 + np] = v;
  ((__fp16*)((char*)ws + WS_TVH_BYTE))[t * 128 + np] = (__fp16)v;
  PK2 pk; pk.h[0] = (__fp16)(q * INV_S); pk.h[1] = (__fp16)k;
  ((uint32_t*)ws)[WS_TQK + t * 128 + np] = pk.u;
  __syncthreads();
  if (np < 8) {
    float s = 0.f;
    #pragma unroll
    for (int mm = 0; mm < 15; ++mm) s += lq[np * 16 + mm] * lk[np * 16 + mm];
    ws[t * 8 + np] = s * INV_S;
  }
}

// ---------- pack all 4 weight matrices into A-fragment order (f16) ----------
__global__ void pack_frags(const float* __restrict__ Wq, const float* __restrict__ bq,
                           const float* __restrict__ Wk, const float* __restrict__ bk,
                           const float* __restrict__ Wv, const float* __restrict__ bv,
                           const float* __restrict__ Wo, const float* __restrict__ bo,
                           float* __restrict__ ws) {
  const int idx = blockIdx.x * 1024 + threadIdx.x;   // 32 x 1024 = 32768
  const int mat = idx >> 13, r = idx & 8191;
  const int nt = r >> 10, kk = (r >> 8) & 3, l = (r >> 2) & 63, d = r & 3;
  const int mm = l & 15;
  const int i0 = kk * 32 + ((l >> 4) << 3) + 2 * d;
  float v0 = 0.f, v1 = 0.f;
  if (mat < 3) {
    const float* W = (mat == 0) ? Wq : (mat == 1) ? Wk : Wv;
    const float* b = (mat == 0) ? bq : (mat == 1) ? bk : bv;
    if (mm < 15) {
      const int col = nt * 15 + mm;
      const int ia = i0, ib = i0 + 1;
      v0 = (ia < 120) ? W[ia * M_D + col] : (ia == 120 ? b[col] : 0.f);
      v1 = (ib < 120) ? W[ib * M_D + col] : (ib == 120 ? b[col] : 0.f);
      if (mat == 0) { v0 *= INV_S; v1 *= INV_S; }
    }
  } else {
    const int n = nt * 16 + mm;
    if (n < M_D) {
      #pragma unroll
      for (int e = 0; e < 2; ++e) {
        const int ip = i0 + e;
        const int hi = ip >> 4, mi = ip & 15;
        float vv = 0.f;
        if (mi < 15) vv = Wo[(hi * 15 + mi) * M_D + n];
        else if (ip == 15) vv = bo[n];
        if (e == 0) v0 = vv; else v1 = vv;
      }
    }
  }
  PK2 pk; pk.h[0] = (__fp16)v0; pk.h[1] = (__fp16)v1;
  ((uint32_t*)ws)[WS_QF + idx] = pk.u;
}

// ---------- dyn f32 -> f16 table, 256B rows, pad halves zeroed ----------
__global__ void cvt_dyn(const float* __restrict__ dyn, __fp16* __restrict__ d16, int rows) {
  const int i = blockIdx.x * 256 + threadIdx.x;
  const int row = i >> 4, sub = i & 15;
  if (row < rows) {
    BFrag o;
    if (sub == 15) { o.u[0] = 0; o.u[1] = 0; o.u[2] = 0; o.u[3] = 0; }
    else {
      const float* src = dyn + (long)row * M_D + sub * 8;
      const f32x4 a = __builtin_nontemporal_load((const f32x4*)src);
      const f32x4 b = __builtin_nontemporal_load((const f32x4*)(src + 4));
      o.h2[0] = __builtin_amdgcn_cvt_pkrtz(a[0], a[1]);
      o.h2[1] = __builtin_amdgcn_cvt_pkrtz(a[2], a[3]);
      o.h2[2] = __builtin_amdgcn_cvt_pkrtz(b[0], b[1]);
      o.h2[3] = __builtin_amdgcn_cvt_pkrtz(b[2], b[3]);
    }
    *(f16x8*)(d16 + (long)row * 128 + sub * 8) = o.v;
  }
}

// ---------- stage 1: hash + deep-burst gather -> interpolated f16 rows ----------
__launch_bounds__(256, 2)
__global__ void gather_feat(const float* __restrict__ qpts, const __fp16* __restrict__ dyn16,
                            const int* __restrict__ hbuf, __fp16* __restrict__ feat, int M) {
  const int l = threadIdx.x & 63, wv = threadIdx.x >> 6;
  const int g = l >> 4, pl = l & 15;
  const int T = (M + 15) >> 4;
  for (int tile = blockIdx.x * 4 + wv; tile < T; tile += gridDim.x * 4) {
    const int pid = (tile << 4) + pl;
    const int p = (pid < M) ? pid : (M - 1);
    const float px = qpts[3 * p], py = qpts[3 * p + 1], pz = qpts[3 * p + 2];
    const float gx = px / 0.1f, gy = py / 0.1f, gz = pz / 0.1f;
    const float fx = floorf(gx), fy = floorf(gy), fz = floorf(gz);
    const float rx = gx - fx, ry = gy - fy, rz = gz - fz;
    const int bx = (int)fx, by = (int)fy, bz = (int)fz;

    int voff[8]; float wcv[8];
    #pragma unroll
    for (int c = 0; c < 8; ++c) {
      const int ox = c & 1, oy = (c >> 1) & 1, oz = c >> 2;
      const uint32_t hh = (uint32_t)(bx + ox) * 73856093u +
                          (uint32_t)(by + oy) * 19349669u +
                          (uint32_t)(bz + oz) * 83492791u;
      const int vc = hbuf[hh & TABLE_MASK];
      const float wc = (ox ? rx : 1.f - rx) * (oy ? ry : 1.f - ry) * (oz ? rz : 1.f - rz);
      wcv[c] = (vc >= 0) ? wc : 0.f;
      voff[c] = ((vc >= 0) ? vc : 0) * 128 + g * 8;
    }

    __fp16* frow = feat + (long)pid * 128 + g * 8;
    f16x8 va[8], vb[8];
    #pragma unroll
    for (int c = 0; c < 8; ++c) va[c] = *(const f16x8*)(dyn16 + voff[c]);
    #pragma unroll
    for (int c = 0; c < 8; ++c) vb[c] = *(const f16x8*)(dyn16 + voff[c] + 32);

    auto PROC = [&](int kk, f16x8* vk) {
      f32x4 accA = {0, 0, 0, 0}, accB = {0, 0, 0, 0};
      #pragma unroll
      for (int c = 0; c < 8; ++c) {
        const float wc = wcv[c];
        const f16x8 v8 = vk[c];
        accA[0] = fmaf((float)v8[0], wc, accA[0]);
        accA[1] = fmaf((float)v8[1], wc, accA[1]);
        accA[2] = fmaf((float)v8[2], wc, accA[2]);
        accA[3] = fmaf((float)v8[3], wc, accA[3]);
        accB[0] = fmaf((float)v8[4], wc, accB[0]);
        accB[1] = fmaf((float)v8[5], wc, accB[1]);
        accB[2] = fmaf((float)v8[6], wc, accB[2]);
        accB[3] = fmaf((float)v8[7], wc, accB[3]);
      }
      if (kk == 3 && g == 3) accA[0] = 1.0f;   // bias slot k=120 (pads are zero)
      BFrag o;
      o.h2[0] = __builtin_amdgcn_cvt_pkrtz(accA[0], accA[1]);
      o.h2[1] = __builtin_amdgcn_cvt_pkrtz(accA[2], accA[3]);
      o.h2[2] = __builtin_amdgcn_cvt_pkrtz(accB[0], accB[1]);
      o.h2[3] = __builtin_amdgcn_cvt_pkrtz(accB[2], accB[3]);
      if (pid < M) __builtin_nontemporal_store(o.v, (f16x8*)(frow + kk * 32));
    };

    PROC(0, va);
    #pragma unroll
    for (int c = 0; c < 8; ++c) va[c] = *(const f16x8*)(dyn16 + voff[c] + 64);
    PROC(1, vb);
    #pragma unroll
    for (int c = 0; c < 8; ++c) vb[c] = *(const f16x8*)(dyn16 + voff[c] + 96);
    PROC(2, va);
    PROC(3, vb);
  }
}

// ---------- stage 2: fused-per-head MFMA attention, 256-thr blocks, high occupancy ----------
__launch_bounds__(256, 4)   // VGPR cap 128; no LDS -> up to 4 blocks/CU = 16 waves/CU
__global__ void mfma_main(const int* __restrict__ qtimes, const __fp16* __restrict__ feat,
                          const float* __restrict__ ws, float* __restrict__ out, int M) {
  const uint32_t* wqg = (const uint32_t*)ws + WS_QF;   // frag streams (L2-resident)
  const uint32_t* wkg = wqg + 8192;
  const uint32_t* wvg = wqg + 16384;
  const uint32_t* wog = wqg + 24576;
  const uint32_t* TQK = (const uint32_t*)ws + WS_TQK;  // time tables
  const __fp16*   TVh = (const __fp16*)((const char*)ws + WS_TVH_BYTE);
  const float*    S11 = ws;

  const int tid = threadIdx.x;
  const int l = tid & 63, wv = tid >> 6;
  const int g = l >> 4, pl = l & 15, c0 = g << 2;

  const int T = (M + 15) >> 4;
  for (int tile = blockIdx.x * 4 + wv; tile < T; tile += gridDim.x * 4) {
    const int pid = (tile << 4) + pl;
    const bool valid = (pid < M);
    const int p = valid ? pid : (M - 1);
    const int tm = qtimes[p] % MOD_T;

    // ---- sequential fragment loads (stage-1 output), cached ----
    BFrag bf[4];
    const __fp16* frow = feat + (long)p * 128 + g * 8;
    #pragma unroll
    for (int kk = 0; kk < 4; ++kk)
      bf[kk].v = *(const f16x8*)(frow + kk * 32);

    // ---- fused per-head: QK GEMM -> scores -> softmax (transients die per nt) ----
    float a_[8], b_[8];
    #pragma unroll
    for (int nt = 0; nt < 8; ++nt) {
      f32x4 zq = {0,0,0,0}, zk = {0,0,0,0};
      #pragma unroll
      for (int kk = 0; kk < 4; ++kk) {
        const int off = nt * 1024 + kk * 256 + l * 4;
        f16x8 a0 = *(const f16x8*)(wqg + off);
        f16x8 a1 = *(const f16x8*)(wkg + off);
        zq = __builtin_amdgcn_mfma_f32_16x16x32_f16(a0, bf[kk].v, zq, 0, 0, 0);
        zk = __builtin_amdgcn_mfma_f32_16x16x32_f16(a1, bf[kk].v, zk, 0, 0, 0);
      }
      const u32x4 tqk = *(const u32x4*)(TQK + tm * 128 + nt * 16 + c0);
      float s00 = 0.f, s01 = 0.f, s10 = 0.f;
      #pragma unroll
      for (int r = 0; r < 4; ++r) {
        const float qv = zq[r], kv = zk[r];
        PK2 tt; tt.u = tqk[r];
        const float tqs = (float)tt.h[0], tk = (float)tt.h[1];
        s00 = fmaf(qv, kv, s00);
        s01 = fmaf(qv, tk, s01);
        s10 = fmaf(tqs, kv, s10);
      }
      s00 += __shfl_xor(s00, 16); s00 += __shfl_xor(s00, 32);
      s01 += __shfl_xor(s01, 16); s01 += __shfl_xor(s01, 32);
      s10 += __shfl_xor(s10, 16); s10 += __shfl_xor(s10, 32);
      const float s11 = S11[tm * 8 + nt];
      const float m0 = fmaxf(s00, s01), m1 = fmaxf(s10, s11);
      const float e00 = __expf(s00 - m0), e01 = __expf(s01 - m0);
      const float e10 = __expf(s10 - m1), e11 = __expf(s11 - m1);
      const float r0 = 1.f / (e00 + e01), r1 = 1.f / (e10 + e11);
      a_[nt] = 0.5f * (e00 * r0 + e10 * r1);
      b_[nt] = 0.5f * (e01 * r0 + e11 * r1);
    }

    // ---- per-head V GEMM + combine (zv dies per nt) ----
    uint32_t cdw[8][2];
    #pragma unroll
    for (int nt = 0; nt < 8; ++nt) {
      f32x4 zv = {0,0,0,0};
      #pragma unroll
      for (int kk = 0; kk < 4; ++kk) {
        f16x8 a2 = *(const f16x8*)(wvg + nt * 1024 + kk * 256 + l * 4);
        zv = __builtin_amdgcn_mfma_f32_16x16x32_f16(a2, bf[kk].v, zv, 0, 0, 0);
      }
      const f16x4v th = *(const f16x4v*)(TVh + tm * 128 + nt * 16 + c0);
      f32x4 cv;
      #pragma unroll
      for (int r = 0; r < 4; ++r) cv[r] = a_[nt] * zv[r] + b_[nt] * (float)th[r];
      if (nt == 0 && g == 3) cv[3] = 1.0f;
      PK2 p0, p1;
      p0.h = __builtin_amdgcn_cvt_pkrtz(cv[0], cv[1]);
      p1.h = __builtin_amdgcn_cvt_pkrtz(cv[2], cv[3]);
      cdw[nt][0] = p0.u; cdw[nt][1] = p1.u;
    }

    // ---- redistribute comb (D-layout) -> B-fragments for O GEMM ----
    const int src0 = pl | ((g & 1) << 5);
    const int src1 = src0 + 16;
    const bool hsel = (g >= 2);
    BFrag bco[4];
    #pragma unroll
    for (int kk = 0; kk < 4; ++kk) {
      #pragma unroll
      for (int d = 0; d < 4; ++d) {
        const int s = (d >= 2) ? src1 : src0;
        const int vlo = __shfl((int)cdw[2 * kk][d & 1], s, 64);
        const int vhi = __shfl((int)cdw[2 * kk + 1][d & 1], s, 64);
        bco[kk].u[d] = hsel ? (uint32_t)vhi : (uint32_t)vlo;
      }
    }

    // ---- O GEMM + store ----
    float* orow = out + (long)p * M_D;
    #pragma unroll
    for (int nt = 0; nt < 8; ++nt) {
      f32x4 zo = {0,0,0,0};
      #pragma unroll
      for (int kk = 0; kk < 4; ++kk) {
        f16x8 a3 = *(const f16x8*)(wog + nt * 1024 + kk * 256 + l * 4);
        zo = __builtin_amdgcn_mfma_f32_16x16x32_f16(a3, bco[kk].v, zo, 0, 0, 0);
      }
      if (valid && (nt < 7 || g < 2))
        *(f32x4*)(orow + nt * 16 + c0) = zo;
    }
  }
}

// ---------- fallback: merged kernel (round-9 structure, padded f16 table) ----------
template <int USE16>
__launch_bounds__(512, 2)
__global__ void merged_main(const float* __restrict__ qpts, const int* __restrict__ qtimes,
                            const float* __restrict__ dyn,  const __fp16* __restrict__ dyn16,
                            const int* __restrict__ hbuf,
                            const float* __restrict__ Wq, const float* __restrict__ bq,
                            const float* __restrict__ Wk, const float* __restrict__ bk,
                            const float* __restrict__ Wv, const float* __restrict__ bv,
                            const float* __restrict__ Wo, const float* __restrict__ bo,
                            const float* __restrict__ ws, float* __restrict__ out, int M) {
  __shared__ __align__(16) uint32_t wlds[4 * 8192];
  const int tid = threadIdx.x;
  for (int idx = tid; idx < 32768; idx += 512) {
    const int mat = idx >> 13, r = idx & 8191;
    const int nt = r >> 10, kk = (r >> 8) & 3, l = (r >> 2) & 63, d = r & 3;
    const int mm = l & 15;
    const int i0 = kk * 32 + ((l >> 4) << 3) + 2 * d;
    float v0 = 0.f, v1 = 0.f;
    if (mat < 3) {
      const float* W = (mat == 0) ? Wq : (mat == 1) ? Wk : Wv;
      const float* b = (mat == 0) ? bq : (mat == 1) ? bk : bv;
      if (mm < 15) {
        const int col = nt * 15 + mm;
        const int ia = i0, ib = i0 + 1;
        v0 = (ia < 120) ? W[ia * M_D + col] : (ia == 120 ? b[col] : 0.f);
        v1 = (ib < 120) ? W[ib * M_D + col] : (ib == 120 ? b[col] : 0.f);
        if (mat == 0) { v0 *= INV_S; v1 *= INV_S; }
      }
    } else {
      const int n = nt * 16 + mm;
      if (n < M_D) {
        #pragma unroll
        for (int e = 0; e < 2; ++e) {
          const int ip = i0 + e;
          const int hi = ip >> 4, mi = ip & 15;
          float vv = 0.f;
          if (mi < 15) vv = Wo[(hi * 15 + mi) * M_D + n];
          else if (ip == 15) vv = bo[n];
          if (e == 0) v0 = vv; else v1 = vv;
        }
      }
    }
    PK2 pk; pk.h[0] = (__fp16)v0; pk.h[1] = (__fp16)v1;
    wlds[idx] = pk.u;
  }
  __syncthreads();

  const uint32_t* wq = wlds;
  const uint32_t* wk = wlds + 8192;
  const uint32_t* wvm = wlds + 2 * 8192;
  const uint32_t* wo = wlds + 3 * 8192;
  const int l = tid & 63, wv = tid >> 6;
  const int g = l >> 4, pl = l & 15, c0 = g << 2;
  const float* S11 = ws;
  const float* TVt = ws + WS_TV;
  const uint32_t* TQK = (const uint32_t*)ws + WS_TQK;

  const int T = (M + 15) >> 4;
  for (int tile = blockIdx.x * 8 + wv; tile < T; tile += gridDim.x * 8) {
    const int pid = (tile << 4) + pl;
    const int p = (pid < M) ? pid : (M - 1);
    const float px = qpts[3 * p], py = qpts[3 * p + 1], pz = qpts[3 * p + 2];
    const int tm = qtimes[p] % MOD_T;
    const float gx = px / 0.1f, gy = py / 0.1f, gz = pz / 0.1f;
    const float fx = floorf(gx), fy = floorf(gy), fz = floorf(gz);
    const float rx = gx - fx, ry = gy - fy, rz = gz - fz;
    const int bx = (int)fx, by = (int)fy, bz = (int)fz;
    const int i0g = g * 8;
    int voff[8]; float wcv[8];
    #pragma unroll
    for (int c = 0; c < 8; ++c) {
      const int ox = c & 1, oy = (c >> 1) & 1, oz = c >> 2;
      const uint32_t hh = (uint32_t)(bx + ox) * 73856093u +
                          (uint32_t)(by + oy) * 19349669u +
                          (uint32_t)(bz + oz) * 83492791u;
      const int vc = hbuf[hh & TABLE_MASK];
      const float wc = (ox ? rx : 1.f - rx) * (oy ? ry : 1.f - ry) * (oz ? rz : 1.f - rz);
      wcv[c] = (vc >= 0) ? wc : 0.f;
      const int vr = (vc >= 0) ? vc : 0;
      voff[c] = (USE16 ? vr * 128 : vr * M_D) + i0g;
    }
    BFrag bf[4];
    #pragma unroll
    for (int kk = 0; kk < 4; ++kk) {
      f32x4 accA = {0, 0, 0, 0}, accB = {0, 0, 0, 0};
      if (kk < 3 || g < 3) {
        #pragma unroll
        for (int c = 0; c < 8; ++c) {
          const float wc = wcv[c];
          if (USE16) {
            const f16x8 v8 = *(const f16x8*)(dyn16 + voff[c] + kk * 32);
            accA[0] = fmaf((float)v8[0], wc, accA[0]);
            accA[1] = fmaf((float)v8[1], wc, accA[1]);
            accA[2] = fmaf((float)v8[2], wc, accA[2]);
            accA[3] = fmaf((float)v8[3], wc, accA[3]);
            accB[0] = fmaf((float)v8[4], wc, accB[0]);
            accB[1] = fmaf((float)v8[5], wc, accB[1]);
            accB[2] = fmaf((float)v8[6], wc, accB[2]);
            accB[3] = fmaf((float)v8[7], wc, accB[3]);
          } else {
            const float* fr = dyn + voff[c];
            f32x4 lo4 = *(const f32x4*)(fr + kk * 32);
            f32x4 hi4 = *(const f32x4*)(fr + kk * 32 + 4);
            accA += lo4 * wc;
            accB += hi4 * wc;
          }
        }
      }
      if (kk == 3 && g == 3) accA[0] = 1.0f;
      bf[kk].h2[0] = __builtin_amdgcn_cvt_pkrtz(accA[0], accA[1]);
      bf[kk].h2[1] = __builtin_amdgcn_cvt_pkrtz(accA[2], accA[3]);
      bf[kk].h2[2] = __builtin_amdgcn_cvt_pkrtz(accB[0], accB[1]);
      bf[kk].h2[3] = __builtin_amdgcn_cvt_pkrtz(accB[2], accB[3]);
    }
    float a_[8], b_[8];
    #pragma unroll
    for (int nt = 0; nt < 8; ++nt) {
      f32x4 zq = {0,0,0,0}, zk = {0,0,0,0};
      #pragma unroll
      for (int kk = 0; kk < 4; ++kk) {
        const int off = nt * 1024 + kk * 256 + l * 4;
        f16x8 a0 = *(const f16x8*)(wq + off);
        f16x8 a1 = *(const f16x8*)(wk + off);
        zq = __builtin_amdgcn_mfma_f32_16x16x32_f16(a0, bf[kk].v, zq, 0, 0, 0);
        zk = __builtin_amdgcn_mfma_f32_16x16x32_f16(a1, bf[kk].v, zk, 0, 0, 0);
      }
      const u32x4 tqk = *(const u32x4*)(TQK + tm * 128 + nt * 16 + c0);
      float s00 = 0.f, s01 = 0.f, s10 = 0.f;
      #pragma unroll
      for (int r = 0; r < 4; ++r) {
        const float qv = zq[r], kv = zk[r];
        PK2 tt; tt.u = tqk[r];
        s00 = fmaf(qv, kv, s00);
        s01 = fmaf(qv, (float)tt.h[1], s01);
        s10 = fmaf((float)tt.h[0], kv, s10);
      }
      s00 += __shfl_xor(s00, 16); s00 += __shfl_xor(s00, 32);
      s01 += __shfl_xor(s01, 16); s01 += __shfl_xor(s01, 32);
      s10 += __shfl_xor(s10, 16); s10 += __shfl_xor(s10, 32);
      const float s11 = S11[tm * 8 + nt];
      const float m0 = fmaxf(s00, s01), m1 = fmaxf(s10, s11);
      const float e00 = __expf(s00 - m0), e01 = __expf(s01 - m0);
      const float e10 = __expf(s10 - m1), e11 = __expf(s11 - m1);
      const float r0 = 1.f / (e00 + e01), r1 = 1.f / (e10 + e11);
      a_[nt] = 0.5f * (e00 * r0 + e10 * r1);
      b_[nt] = 0.5f * (e01 * r0 + e11 * r1);
    }
    uint32_t cdw[8][2];
    #pragma unroll
    for (int nt = 0; nt < 8; ++nt) {
      f32x4 zv = {0,0,0,0};
      #pragma unroll
      for (int kk = 0; kk < 4; ++kk) {
        f16x8 a2 = *(const f16x8*)(wvm + nt * 1024 + kk * 256 + l * 4);
        zv = __builtin_amdgcn_mfma_f32_16x16x32_f16(a2, bf[kk].v, zv, 0, 0, 0);
      }
      const f32x4 tvv = *(const f32x4*)(TVt + tm * 128 + nt * 16 + c0);
      f32x4 cv;
      #pragma unroll
      for (int r = 0; r < 4; ++r) cv[r] = a_[nt] * zv[r] + b_[nt] * tvv[r];
      if (nt == 0 && g == 3) cv[3] = 1.0f;
      PK2 p0, p1;
      p0.h = __builtin_amdgcn_cvt_pkrtz(cv[0], cv[1]);
      p1.h = __builtin_amdgcn_cvt_pkrtz(cv[2], cv[3]);
      cdw[nt][0] = p0.u; cdw[nt][1] = p1.u;
    }
    const int src0 = pl | ((g & 1) << 5);
    const int src1 = src0 + 16;
    const bool hsel = (g >= 2);
    BFrag bco[4];
    #pragma unroll
    for (int kk = 0; kk < 4; ++kk) {
      #pragma unroll
      for (int d = 0; d < 4; ++d) {
        const int s = (d >= 2) ? src1 : src0;
        const int vlo = __shfl((int)cdw[2 * kk][d & 1], s, 64);
        const int vhi = __shfl((int)cdw[2 * kk + 1][d & 1], s, 64);
        bco[kk].u[d] = hsel ? (uint32_t)vhi : (uint32_t)vlo;
      }
    }
    float* orow = out + (long)pid * M_D;
    #pragma unroll
    for (int nt = 0; nt < 8; ++nt) {
      f32x4 zo = {0,0,0,0};
      #pragma unroll
      for (int kk = 0; kk < 4; ++kk) {
        f16x8 a3 = *(const f16x8*)(wo + nt * 1024 + kk * 256 + l * 4);
        zo = __builtin_amdgcn_mfma_f32_16x16x32_f16(a3, bco[kk].v, zo, 0, 0, 0);
      }
      if (pid < M && (nt < 7 || g < 2))
        *(f32x4*)(orow + nt * 16 + c0) = zo;
    }
  }
}

extern "C" void kernel_launch(void* const* d_in, const int* in_sizes, int n_in,
                              void* d_out, int out_size, void* d_ws, size_t ws_size,
                              hipStream_t stream) {
  const float* qpts   = (const float*)d_in[0];
  const int*   qtimes = (const int*)d_in[1];
  const float* dyn    = (const float*)d_in[2];
  const float* temb   = (const float*)d_in[3];
  const int*   hbuf   = (const int*)d_in[4];
  const float* Wq = (const float*)d_in[5];
  const float* bq = (const float*)d_in[6];
  const float* Wk = (const float*)d_in[7];
  const float* bk = (const float*)d_in[8];
  const float* Wv = (const float*)d_in[9];
  const float* bv = (const float*)d_in[10];
  const float* Wo = (const float*)d_in[11];
  const float* bo = (const float*)d_in[12];
  float* out = (float*)d_out;
  float* ws  = (float*)d_ws;
  const int M = in_sizes[1];
  const int ndyn = in_sizes[2];
  const int rows = ndyn / M_D;

  hipLaunchKernelGGL(precomp_time, dim3(MOD_T), dim3(128), 0, stream,
                     temb, Wq, bq, Wk, bk, Wv, bv, ws);

  const size_t dyn16_bytes = (size_t)rows * 256;
  const size_t need16 = WS_DYN16_BYTE + dyn16_bytes;
  const size_t feat_off = (need16 + 255) & ~255ull;
  const size_t T16 = (size_t)(((M + 15) / 16) * 16);
  const size_t needF = feat_off + T16 * 256;

  if (ws_size >= need16) {
    __fp16* d16 = (__fp16*)((char*)d_ws + WS_DYN16_BYTE);
    const int nchunk = rows * 16;
    hipLaunchKernelGGL(cvt_dyn, dim3((nchunk + 255) / 256), dim3(256), 0, stream,
                       dyn, d16, rows);
    if (ws_size >= needF) {
      __fp16* feat = (__fp16*)((char*)d_ws + feat_off);
      hipLaunchKernelGGL(pack_frags, dim3(32), dim3(1024), 0, stream,
                         Wq, bq, Wk, bk, Wv, bv, Wo, bo, ws);
      hipLaunchKernelGGL(gather_feat, dim3(2048), dim3(256), 0, stream,
                         qpts, d16, hbuf, feat, M);
      hipLaunchKernelGGL(mfma_main, dim3(2048), dim3(256), 0, stream,
                         qtimes, feat, ws, out, M);
    } else {
      hipLaunchKernelGGL(merged_main<1>, dim3(256), dim3(512), 0, stream,
                         qpts, qtimes, dyn, d16, hbuf,
                         Wq, bq, Wk, bk, Wv, bv, Wo, bo, ws, out, M);
    }
  } else {
    hipLaunchKernelGGL(merged_main<0>, dim3(256), dim3(512), 0, stream,
                       qpts, qtimes, dyn, (const __fp16*)nullptr, hbuf,
                       Wq, bq, Wk, bk, Wv, bv, Wo, bo, ws, out, M);
  }
}

// Round 17
// 1048.749 us; speedup vs baseline: 1.4603x; 1.4603x over previous
//
#include <hip/hip_runtime.h>
#include <math.h>

#define M_D   120
#define MOD_T 201
#define TABLE_MASK 0xFFFFFu
#define INV_S 0.25819888974716115f   // 1/sqrt(15)

// ws float-region: S11[201*8] @0 ; TV'[201*128] @1608 ; TQK'[201*128] (u32) @27336
// frag dwords @53248 (byte 212992, 131072 B) ; TVh f16 @byte 344064 (51456 B)
// dyn16 @ 1 MB ; feat after dyn16
#define WS_TV   1608
#define WS_TQK  27336
#define WS_QF   53248
#define WS_TVH_BYTE 344064ull
#define WS_DYN16_BYTE (1ull << 20)

typedef float    f32x4 __attribute__((ext_vector_type(4)));
typedef uint32_t u32x4 __attribute__((ext_vector_type(4)));
typedef __fp16   f16x2v __attribute__((ext_vector_type(2)));
typedef __fp16   f16x4v __attribute__((ext_vector_type(4)));
typedef __fp16   f16x8 __attribute__((ext_vector_type(8)));

union PK2 { f16x2v h; uint32_t u; };
union BFrag { f16x8 v; f16x2v h2[4]; uint32_t u[4]; };

// ---------- precompute padded time-token tables (+ f16 TV copy) ----------
__global__ void precomp_time(const float* __restrict__ temb,
                             const float* __restrict__ Wq, const float* __restrict__ bq,
                             const float* __restrict__ Wk, const float* __restrict__ bk,
                             const float* __restrict__ Wv, const float* __restrict__ bv,
                             float* __restrict__ ws) {
  const int t = blockIdx.x, np = threadIdx.x;
  const int h = np >> 4, m = np & 15;
  const bool valid = (m < 15);
  const int col = h * 15 + m;
  __shared__ float lq[128], lk[128];
  float q = 0.f, k = 0.f, v = 0.f;
  if (valid) {
    q = bq[col]; k = bk[col]; v = bv[col];
    const float* te = temb + t * M_D;
    for (int i = 0; i < M_D; ++i) {
      float x = te[i];
      q = fmaf(x, Wq[i * M_D + col], q);
      k = fmaf(x, Wk[i * M_D + col], k);
      v = fmaf(x, Wv[i * M_D + col], v);
    }
  }
  lq[np] = q; lk[np] = k;
  ws[WS_TV + t * 128 + np] = v;
  ((__fp16*)((char*)ws + WS_TVH_BYTE))[t * 128 + np] = (__fp16)v;
  PK2 pk; pk.h[0] = (__fp16)(q * INV_S); pk.h[1] = (__fp16)k;
  ((uint32_t*)ws)[WS_TQK + t * 128 + np] = pk.u;
  __syncthreads();
  if (np < 8) {
    float s = 0.f;
    #pragma unroll
    for (int mm = 0; mm < 15; ++mm) s += lq[np * 16 + mm] * lk[np * 16 + mm];
    ws[t * 8 + np] = s * INV_S;
  }
}

// ---------- pack all 4 weight matrices into A-fragment order (f16) ----------
__global__ void pack_frags(const float* __restrict__ Wq, const float* __restrict__ bq,
                           const float* __restrict__ Wk, const float* __restrict__ bk,
                           const float* __restrict__ Wv, const float* __restrict__ bv,
                           const float* __restrict__ Wo, const float* __restrict__ bo,
                           float* __restrict__ ws) {
  const int idx = blockIdx.x * 1024 + threadIdx.x;   // 32 x 1024 = 32768
  const int mat = idx >> 13, r = idx & 8191;
  const int nt = r >> 10, kk = (r >> 8) & 3, l = (r >> 2) & 63, d = r & 3;
  const int mm = l & 15;
  const int i0 = kk * 32 + ((l >> 4) << 3) + 2 * d;
  float v0 = 0.f, v1 = 0.f;
  if (mat < 3) {
    const float* W = (mat == 0) ? Wq : (mat == 1) ? Wk : Wv;
    const float* b = (mat == 0) ? bq : (mat == 1) ? bk : bv;
    if (mm < 15) {
      const int col = nt * 15 + mm;
      const int ia = i0, ib = i0 + 1;
      v0 = (ia < 120) ? W[ia * M_D + col] : (ia == 120 ? b[col] : 0.f);
      v1 = (ib < 120) ? W[ib * M_D + col] : (ib == 120 ? b[col] : 0.f);
      if (mat == 0) { v0 *= INV_S; v1 *= INV_S; }
    }
  } else {
    const int n = nt * 16 + mm;
    if (n < M_D) {
      #pragma unroll
      for (int e = 0; e < 2; ++e) {
        const int ip = i0 + e;
        const int hi = ip >> 4, mi = ip & 15;
        float vv = 0.f;
        if (mi < 15) vv = Wo[(hi * 15 + mi) * M_D + n];
        else if (ip == 15) vv = bo[n];
        if (e == 0) v0 = vv; else v1 = vv;
      }
    }
  }
  PK2 pk; pk.h[0] = (__fp16)v0; pk.h[1] = (__fp16)v1;
  ((uint32_t*)ws)[WS_QF + idx] = pk.u;
}

// ---------- dyn f32 -> f16 table, 256B rows, pad halves zeroed ----------
__global__ void cvt_dyn(const float* __restrict__ dyn, __fp16* __restrict__ d16, int rows) {
  const int i = blockIdx.x * 256 + threadIdx.x;
  const int row = i >> 4, sub = i & 15;
  if (row < rows) {
    BFrag o;
    if (sub == 15) { o.u[0] = 0; o.u[1] = 0; o.u[2] = 0; o.u[3] = 0; }
    else {
      const float* src = dyn + (long)row * M_D + sub * 8;
      const f32x4 a = __builtin_nontemporal_load((const f32x4*)src);
      const f32x4 b = __builtin_nontemporal_load((const f32x4*)(src + 4));
      o.h2[0] = __builtin_amdgcn_cvt_pkrtz(a[0], a[1]);
      o.h2[1] = __builtin_amdgcn_cvt_pkrtz(a[2], a[3]);
      o.h2[2] = __builtin_amdgcn_cvt_pkrtz(b[0], b[1]);
      o.h2[3] = __builtin_amdgcn_cvt_pkrtz(b[2], b[3]);
    }
    *(f16x8*)(d16 + (long)row * 128 + sub * 8) = o.v;
  }
}

// ---------- stage 1: hash + deep-burst gather -> interpolated f16 rows ----------
__launch_bounds__(256, 2)
__global__ void gather_feat(const float* __restrict__ qpts, const __fp16* __restrict__ dyn16,
                            const int* __restrict__ hbuf, __fp16* __restrict__ feat, int M) {
  const int l = threadIdx.x & 63, wv = threadIdx.x >> 6;
  const int g = l >> 4, pl = l & 15;
  const int T = (M + 15) >> 4;
  for (int tile = blockIdx.x * 4 + wv; tile < T; tile += gridDim.x * 4) {
    const int pid = (tile << 4) + pl;
    const int p = (pid < M) ? pid : (M - 1);
    const float px = qpts[3 * p], py = qpts[3 * p + 1], pz = qpts[3 * p + 2];
    const float gx = px / 0.1f, gy = py / 0.1f, gz = pz / 0.1f;
    const float fx = floorf(gx), fy = floorf(gy), fz = floorf(gz);
    const float rx = gx - fx, ry = gy - fy, rz = gz - fz;
    const int bx = (int)fx, by = (int)fy, bz = (int)fz;

    int voff[8]; float wcv[8];
    #pragma unroll
    for (int c = 0; c < 8; ++c) {
      const int ox = c & 1, oy = (c >> 1) & 1, oz = c >> 2;
      const uint32_t hh = (uint32_t)(bx + ox) * 73856093u +
                          (uint32_t)(by + oy) * 19349669u +
                          (uint32_t)(bz + oz) * 83492791u;
      const int vc = hbuf[hh & TABLE_MASK];
      const float wc = (ox ? rx : 1.f - rx) * (oy ? ry : 1.f - ry) * (oz ? rz : 1.f - rz);
      wcv[c] = (vc >= 0) ? wc : 0.f;
      voff[c] = ((vc >= 0) ? vc : 0) * 128 + g * 8;
    }

    __fp16* frow = feat + (long)pid * 128 + g * 8;
    f16x8 va[8], vb[8];
    #pragma unroll
    for (int c = 0; c < 8; ++c) va[c] = *(const f16x8*)(dyn16 + voff[c]);
    #pragma unroll
    for (int c = 0; c < 8; ++c) vb[c] = *(const f16x8*)(dyn16 + voff[c] + 32);

    auto PROC = [&](int kk, f16x8* vk) {
      f32x4 accA = {0, 0, 0, 0}, accB = {0, 0, 0, 0};
      #pragma unroll
      for (int c = 0; c < 8; ++c) {
        const float wc = wcv[c];
        const f16x8 v8 = vk[c];
        accA[0] = fmaf((float)v8[0], wc, accA[0]);
        accA[1] = fmaf((float)v8[1], wc, accA[1]);
        accA[2] = fmaf((float)v8[2], wc, accA[2]);
        accA[3] = fmaf((float)v8[3], wc, accA[3]);
        accB[0] = fmaf((float)v8[4], wc, accB[0]);
        accB[1] = fmaf((float)v8[5], wc, accB[1]);
        accB[2] = fmaf((float)v8[6], wc, accB[2]);
        accB[3] = fmaf((float)v8[7], wc, accB[3]);
      }
      if (kk == 3 && g == 3) accA[0] = 1.0f;   // bias slot k=120 (pads are zero)
      BFrag o;
      o.h2[0] = __builtin_amdgcn_cvt_pkrtz(accA[0], accA[1]);
      o.h2[1] = __builtin_amdgcn_cvt_pkrtz(accA[2], accA[3]);
      o.h2[2] = __builtin_amdgcn_cvt_pkrtz(accB[0], accB[1]);
      o.h2[3] = __builtin_amdgcn_cvt_pkrtz(accB[2], accB[3]);
      if (pid < M) __builtin_nontemporal_store(o.v, (f16x8*)(frow + kk * 32));
    };

    PROC(0, va);
    #pragma unroll
    for (int c = 0; c < 8; ++c) va[c] = *(const f16x8*)(dyn16 + voff[c] + 64);
    PROC(1, vb);
    #pragma unroll
    for (int c = 0; c < 8; ++c) vb[c] = *(const f16x8*)(dyn16 + voff[c] + 96);
    PROC(2, va);
    PROC(3, vb);
  }
}

// ---------- stage 2: fused-per-head MFMA attention (r13 config, cached feat loads) ----------
__launch_bounds__(512, 2)
__global__ void mfma_main(const int* __restrict__ qtimes, const __fp16* __restrict__ feat,
                          const float* __restrict__ ws, float* __restrict__ out, int M) {
  const uint32_t* wqg = (const uint32_t*)ws + WS_QF;   // frag streams (L2-resident)
  const uint32_t* wkg = wqg + 8192;
  const uint32_t* wvg = wqg + 16384;
  const uint32_t* wog = wqg + 24576;
  const uint32_t* TQK = (const uint32_t*)ws + WS_TQK;  // time tables
  const __fp16*   TVh = (const __fp16*)((const char*)ws + WS_TVH_BYTE);
  const float*    S11 = ws;

  const int tid = threadIdx.x;
  const int l = tid & 63, wv = tid >> 6;
  const int g = l >> 4, pl = l & 15, c0 = g << 2;

  const int T = (M + 15) >> 4;
  for (int tile = blockIdx.x * 8 + wv; tile < T; tile += gridDim.x * 8) {
    const int pid = (tile << 4) + pl;
    const bool valid = (pid < M);
    const int p = valid ? pid : (M - 1);
    const int tm = qtimes[p] % MOD_T;

    // ---- sequential fragment loads (stage-1 output), cached ----
    BFrag bf[4];
    const __fp16* frow = feat + (long)p * 128 + g * 8;
    #pragma unroll
    for (int kk = 0; kk < 4; ++kk)
      bf[kk].v = *(const f16x8*)(frow + kk * 32);

    // ---- fused per-head: QK GEMM -> scores -> softmax (transients die per nt) ----
    float a_[8], b_[8];
    #pragma unroll
    for (int nt = 0; nt < 8; ++nt) {
      f32x4 zq = {0,0,0,0}, zk = {0,0,0,0};
      #pragma unroll
      for (int kk = 0; kk < 4; ++kk) {
        const int off = nt * 1024 + kk * 256 + l * 4;
        f16x8 a0 = *(const f16x8*)(wqg + off);
        f16x8 a1 = *(const f16x8*)(wkg + off);
        zq = __builtin_amdgcn_mfma_f32_16x16x32_f16(a0, bf[kk].v, zq, 0, 0, 0);
        zk = __builtin_amdgcn_mfma_f32_16x16x32_f16(a1, bf[kk].v, zk, 0, 0, 0);
      }
      const u32x4 tqk = *(const u32x4*)(TQK + tm * 128 + nt * 16 + c0);
      float s00 = 0.f, s01 = 0.f, s10 = 0.f;
      #pragma unroll
      for (int r = 0; r < 4; ++r) {
        const float qv = zq[r], kv = zk[r];
        PK2 tt; tt.u = tqk[r];
        const float tqs = (float)tt.h[0], tk = (float)tt.h[1];
        s00 = fmaf(qv, kv, s00);
        s01 = fmaf(qv, tk, s01);
        s10 = fmaf(tqs, kv, s10);
      }
      s00 += __shfl_xor(s00, 16); s00 += __shfl_xor(s00, 32);
      s01 += __shfl_xor(s01, 16); s01 += __shfl_xor(s01, 32);
      s10 += __shfl_xor(s10, 16); s10 += __shfl_xor(s10, 32);
      const float s11 = S11[tm * 8 + nt];
      const float m0 = fmaxf(s00, s01), m1 = fmaxf(s10, s11);
      const float e00 = __expf(s00 - m0), e01 = __expf(s01 - m0);
      const float e10 = __expf(s10 - m1), e11 = __expf(s11 - m1);
      const float r0 = 1.f / (e00 + e01), r1 = 1.f / (e10 + e11);
      a_[nt] = 0.5f * (e00 * r0 + e10 * r1);
      b_[nt] = 0.5f * (e01 * r0 + e11 * r1);
    }

    // ---- per-head V GEMM + combine (zv dies per nt) ----
    uint32_t cdw[8][2];
    #pragma unroll
    for (int nt = 0; nt < 8; ++nt) {
      f32x4 zv = {0,0,0,0};
      #pragma unroll
      for (int kk = 0; kk < 4; ++kk) {
        f16x8 a2 = *(const f16x8*)(wvg + nt * 1024 + kk * 256 + l * 4);
        zv = __builtin_amdgcn_mfma_f32_16x16x32_f16(a2, bf[kk].v, zv, 0, 0, 0);
      }
      const f16x4v th = *(const f16x4v*)(TVh + tm * 128 + nt * 16 + c0);
      f32x4 cv;
      #pragma unroll
      for (int r = 0; r < 4; ++r) cv[r] = a_[nt] * zv[r] + b_[nt] * (float)th[r];
      if (nt == 0 && g == 3) cv[3] = 1.0f;
      PK2 p0, p1;
      p0.h = __builtin_amdgcn_cvt_pkrtz(cv[0], cv[1]);
      p1.h = __builtin_amdgcn_cvt_pkrtz(cv[2], cv[3]);
      cdw[nt][0] = p0.u; cdw[nt][1] = p1.u;
    }

    // ---- redistribute comb (D-layout) -> B-fragments for O GEMM ----
    const int src0 = pl | ((g & 1) << 5);
    const int src1 = src0 + 16;
    const bool hsel = (g >= 2);
    BFrag bco[4];
    #pragma unroll
    for (int kk = 0; kk < 4; ++kk) {
      #pragma unroll
      for (int d = 0; d < 4; ++d) {
        const int s = (d >= 2) ? src1 : src0;
        const int vlo = __shfl((int)cdw[2 * kk][d & 1], s, 64);
        const int vhi = __shfl((int)cdw[2 * kk + 1][d & 1], s, 64);
        bco[kk].u[d] = hsel ? (uint32_t)vhi : (uint32_t)vlo;
      }
    }

    // ---- O GEMM + NON-TEMPORAL store ----
    float* orow = out + (long)p * M_D;
    #pragma unroll
    for (int nt = 0; nt < 8; ++nt) {
      f32x4 zo = {0,0,0,0};
      #pragma unroll
      for (int kk = 0; kk < 4; ++kk) {
        f16x8 a3 = *(const f16x8*)(wog + nt * 1024 + kk * 256 + l * 4);
        zo = __builtin_amdgcn_mfma_f32_16x16x32_f16(a3, bco[kk].v, zo, 0, 0, 0);
      }
      if (valid && (nt < 7 || g < 2))
        __builtin_nontemporal_store(zo, (f32x4*)(orow + nt * 16 + c0));
    }
  }
}

// ---------- fallback: merged kernel (round-9 structure, padded f16 table) ----------
template <int USE16>
__launch_bounds__(512, 2)
__global__ void merged_main(const float* __restrict__ qpts, const int* __restrict__ qtimes,
                            const float* __restrict__ dyn,  const __fp16* __restrict__ dyn16,
                            const int* __restrict__ hbuf,
                            const float* __restrict__ Wq, const float* __restrict__ bq,
                            const float* __restrict__ Wk, const float* __restrict__ bk,
                            const float* __restrict__ Wv, const float* __restrict__ bv,
                            const float* __restrict__ Wo, const float* __restrict__ bo,
                            const float* __restrict__ ws, float* __restrict__ out, int M) {
  __shared__ __align__(16) uint32_t wlds[4 * 8192];
  const int tid = threadIdx.x;
  for (int idx = tid; idx < 32768; idx += 512) {
    const int mat = idx >> 13, r = idx & 8191;
    const int nt = r >> 10, kk = (r >> 8) & 3, l = (r >> 2) & 63, d = r & 3;
    const int mm = l & 15;
    const int i0 = kk * 32 + ((l >> 4) << 3) + 2 * d;
    float v0 = 0.f, v1 = 0.f;
    if (mat < 3) {
      const float* W = (mat == 0) ? Wq : (mat == 1) ? Wk : Wv;
      const float* b = (mat == 0) ? bq : (mat == 1) ? bk : bv;
      if (mm < 15) {
        const int col = nt * 15 + mm;
        const int ia = i0, ib = i0 + 1;
        v0 = (ia < 120) ? W[ia * M_D + col] : (ia == 120 ? b[col] : 0.f);
        v1 = (ib < 120) ? W[ib * M_D + col] : (ib == 120 ? b[col] : 0.f);
        if (mat == 0) { v0 *= INV_S; v1 *= INV_S; }
      }
    } else {
      const int n = nt * 16 + mm;
      if (n < M_D) {
        #pragma unroll
        for (int e = 0; e < 2; ++e) {
          const int ip = i0 + e;
          const int hi = ip >> 4, mi = ip & 15;
          float vv = 0.f;
          if (mi < 15) vv = Wo[(hi * 15 + mi) * M_D + n];
          else if (ip == 15) vv = bo[n];
          if (e == 0) v0 = vv; else v1 = vv;
        }
      }
    }
    PK2 pk; pk.h[0] = (__fp16)v0; pk.h[1] = (__fp16)v1;
    wlds[idx] = pk.u;
  }
  __syncthreads();

  const uint32_t* wq = wlds;
  const uint32_t* wk = wlds + 8192;
  const uint32_t* wvm = wlds + 2 * 8192;
  const uint32_t* wo = wlds + 3 * 8192;
  const int l = tid & 63, wv = tid >> 6;
  const int g = l >> 4, pl = l & 15, c0 = g << 2;
  const float* S11 = ws;
  const float* TVt = ws + WS_TV;
  const uint32_t* TQK = (const uint32_t*)ws + WS_TQK;

  const int T = (M + 15) >> 4;
  for (int tile = blockIdx.x * 8 + wv; tile < T; tile += gridDim.x * 8) {
    const int pid = (tile << 4) + pl;
    const int p = (pid < M) ? pid : (M - 1);
    const float px = qpts[3 * p], py = qpts[3 * p + 1], pz = qpts[3 * p + 2];
    const int tm = qtimes[p] % MOD_T;
    const float gx = px / 0.1f, gy = py / 0.1f, gz = pz / 0.1f;
    const float fx = floorf(gx), fy = floorf(gy), fz = floorf(gz);
    const float rx = gx - fx, ry = gy - fy, rz = gz - fz;
    const int bx = (int)fx, by = (int)fy, bz = (int)fz;
    const int i0g = g * 8;
    int voff[8]; float wcv[8];
    #pragma unroll
    for (int c = 0; c < 8; ++c) {
      const int ox = c & 1, oy = (c >> 1) & 1, oz = c >> 2;
      const uint32_t hh = (uint32_t)(bx + ox) * 73856093u +
                          (uint32_t)(by + oy) * 19349669u +
                          (uint32_t)(bz + oz) * 83492791u;
      const int vc = hbuf[hh & TABLE_MASK];
      const float wc = (ox ? rx : 1.f - rx) * (oy ? ry : 1.f - ry) * (oz ? rz : 1.f - rz);
      wcv[c] = (vc >= 0) ? wc : 0.f;
      const int vr = (vc >= 0) ? vc : 0;
      voff[c] = (USE16 ? vr * 128 : vr * M_D) + i0g;
    }
    BFrag bf[4];
    #pragma unroll
    for (int kk = 0; kk < 4; ++kk) {
      f32x4 accA = {0, 0, 0, 0}, accB = {0, 0, 0, 0};
      if (kk < 3 || g < 3) {
        #pragma unroll
        for (int c = 0; c < 8; ++c) {
          const float wc = wcv[c];
          if (USE16) {
            const f16x8 v8 = *(const f16x8*)(dyn16 + voff[c] + kk * 32);
            accA[0] = fmaf((float)v8[0], wc, accA[0]);
            accA[1] = fmaf((float)v8[1], wc, accA[1]);
            accA[2] = fmaf((float)v8[2], wc, accA[2]);
            accA[3] = fmaf((float)v8[3], wc, accA[3]);
            accB[0] = fmaf((float)v8[4], wc, accB[0]);
            accB[1] = fmaf((float)v8[5], wc, accB[1]);
            accB[2] = fmaf((float)v8[6], wc, accB[2]);
            accB[3] = fmaf((float)v8[7], wc, accB[3]);
          } else {
            const float* fr = dyn + voff[c];
            f32x4 lo4 = *(const f32x4*)(fr + kk * 32);
            f32x4 hi4 = *(const f32x4*)(fr + kk * 32 + 4);
            accA += lo4 * wc;
            accB += hi4 * wc;
          }
        }
      }
      if (kk == 3 && g == 3) accA[0] = 1.0f;
      bf[kk].h2[0] = __builtin_amdgcn_cvt_pkrtz(accA[0], accA[1]);
      bf[kk].h2[1] = __builtin_amdgcn_cvt_pkrtz(accA[2], accA[3]);
      bf[kk].h2[2] = __builtin_amdgcn_cvt_pkrtz(accB[0], accB[1]);
      bf[kk].h2[3] = __builtin_amdgcn_cvt_pkrtz(accB[2], accB[3]);
    }
    float a_[8], b_[8];
    #pragma unroll
    for (int nt = 0; nt < 8; ++nt) {
      f32x4 zq = {0,0,0,0}, zk = {0,0,0,0};
      #pragma unroll
      for (int kk = 0; kk < 4; ++kk) {
        const int off = nt * 1024 + kk * 256 + l * 4;
        f16x8 a0 = *(const f16x8*)(wq + off);
        f16x8 a1 = *(const f16x8*)(wk + off);
        zq = __builtin_amdgcn_mfma_f32_16x16x32_f16(a0, bf[kk].v, zq, 0, 0, 0);
        zk = __builtin_amdgcn_mfma_f32_16x16x32_f16(a1, bf[kk].v, zk, 0, 0, 0);
      }
      const u32x4 tqk = *(const u32x4*)(TQK + tm * 128 + nt * 16 + c0);
      float s00 = 0.f, s01 = 0.f, s10 = 0.f;
      #pragma unroll
      for (int r = 0; r < 4; ++r) {
        const float qv = zq[r], kv = zk[r];
        PK2 tt; tt.u = tqk[r];
        s00 = fmaf(qv, kv, s00);
        s01 = fmaf(qv, (float)tt.h[1], s01);
        s10 = fmaf((float)tt.h[0], kv, s10);
      }
      s00 += __shfl_xor(s00, 16); s00 += __shfl_xor(s00, 32);
      s01 += __shfl_xor(s01, 16); s01 += __shfl_xor(s01, 32);
      s10 += __shfl_xor(s10, 16); s10 += __shfl_xor(s10, 32);
      const float s11 = S11[tm * 8 + nt];
      const float m0 = fmaxf(s00, s01), m1 = fmaxf(s10, s11);
      const float e00 = __expf(s00 - m0), e01 = __expf(s01 - m0);
      const float e10 = __expf(s10 - m1), e11 = __expf(s11 - m1);
      const float r0 = 1.f / (e00 + e01), r1 = 1.f / (e10 + e11);
      a_[nt] = 0.5f * (e00 * r0 + e10 * r1);
      b_[nt] = 0.5f * (e01 * r0 + e11 * r1);
    }
    uint32_t cdw[8][2];
    #pragma unroll
    for (int nt = 0; nt < 8; ++nt) {
      f32x4 zv = {0,0,0,0};
      #pragma unroll
      for (int kk = 0; kk < 4; ++kk) {
        f16x8 a2 = *(const f16x8*)(wvm + nt * 1024 + kk * 256 + l * 4);
        zv = __builtin_amdgcn_mfma_f32_16x16x32_f16(a2, bf[kk].v, zv, 0, 0, 0);
      }
      const f32x4 tvv = *(const f32x4*)(TVt + tm * 128 + nt * 16 + c0);
      f32x4 cv;
      #pragma unroll
      for (int r = 0; r < 4; ++r) cv[r] = a_[nt] * zv[r] + b_[nt] * tvv[r];
      if (nt == 0 && g == 3) cv[3] = 1.0f;
      PK2 p0, p1;
      p0.h = __builtin_amdgcn_cvt_pkrtz(cv[0], cv[1]);
      p1.h = __builtin_amdgcn_cvt_pkrtz(cv[2], cv[3]);
      cdw[nt][0] = p0.u; cdw[nt][1] = p1.u;
    }
    const int src0 = pl | ((g & 1) << 5);
    const int src1 = src0 + 16;
    const bool hsel = (g >= 2);
    BFrag bco[4];
    #pragma unroll
    for (int kk = 0; kk < 4; ++kk) {
      #pragma unroll
      for (int d = 0; d < 4; ++d) {
        const int s = (d >= 2) ? src1 : src0;
        const int vlo = __shfl((int)cdw[2 * kk][d & 1], s, 64);
        const int vhi = __shfl((int)cdw[2 * kk + 1][d & 1], s, 64);
        bco[kk].u[d] = hsel ? (uint32_t)vhi : (uint32_t)vlo;
      }
    }
    float* orow = out + (long)pid * M_D;
    #pragma unroll
    for (int nt = 0; nt < 8; ++nt) {
      f32x4 zo = {0,0,0,0};
      #pragma unroll
      for (int kk = 0; kk < 4; ++kk) {
        f16x8 a3 = *(const f16x8*)(wo + nt * 1024 + kk * 256 + l * 4);
        zo = __builtin_amdgcn_mfma_f32_16x16x32_f16(a3, bco[kk].v, zo, 0, 0, 0);
      }
      if (pid < M && (nt < 7 || g < 2))
        *(f32x4*)(orow + nt * 16 + c0) = zo;
    }
  }
}

extern "C" void kernel_launch(void* const* d_in, const int* in_sizes, int n_in,
                              void* d_out, int out_size, void* d_ws, size_t ws_size,
                              hipStream_t stream) {
  const float* qpts   = (const float*)d_in[0];
  const int*   qtimes = (const int*)d_in[1];
  const float* dyn    = (const float*)d_in[2];
  const float* temb   = (const float*)d_in[3];
  const int*   hbuf   = (const int*)d_in[4];
  const float* Wq = (const float*)d_in[5];
  const float* bq = (const float*)d_in[6];
  const float* Wk = (const float*)d_in[7];
  const float* bk = (const float*)d_in[8];
  const float* Wv = (const float*)d_in[9];
  const float* bv = (const float*)d_in[10];
  const float* Wo = (const float*)d_in[11];
  const float* bo = (const float*)d_in[12];
  float* out = (float*)d_out;
  float* ws  = (float*)d_ws;
  const int M = in_sizes[1];
  const int ndyn = in_sizes[2];
  const int rows = ndyn / M_D;

  hipLaunchKernelGGL(precomp_time, dim3(MOD_T), dim3(128), 0, stream,
                     temb, Wq, bq, Wk, bk, Wv, bv, ws);

  const size_t dyn16_bytes = (size_t)rows * 256;
  const size_t need16 = WS_DYN16_BYTE + dyn16_bytes;
  const size_t feat_off = (need16 + 255) & ~255ull;
  const size_t T16 = (size_t)(((M + 15) / 16) * 16);
  const size_t needF = feat_off + T16 * 256;

  if (ws_size >= need16) {
    __fp16* d16 = (__fp16*)((char*)d_ws + WS_DYN16_BYTE);
    const int nchunk = rows * 16;
    hipLaunchKernelGGL(cvt_dyn, dim3((nchunk + 255) / 256), dim3(256), 0, stream,
                       dyn, d16, rows);
    if (ws_size >= needF) {
      __fp16* feat = (__fp16*)((char*)d_ws + feat_off);
      hipLaunchKernelGGL(pack_frags, dim3(32), dim3(1024), 0, stream,
                         Wq, bq, Wk, bk, Wv, bv, Wo, bo, ws);
      hipLaunchKernelGGL(gather_feat, dim3(2048), dim3(256), 0, stream,
                         qpts, d16, hbuf, feat, M);
      hipLaunchKernelGGL(mfma_main, dim3(512), dim3(512), 0, stream,
                         qtimes, feat, ws, out, M);
    } else {
      hipLaunchKernelGGL(merged_main<1>, dim3(256), dim3(512), 0, stream,
                         qpts, qtimes, dyn, d16, hbuf,
                         Wq, bq, Wk, bk, Wv, bv, Wo, bo, ws, out, M);
    }
  } else {
    hipLaunchKernelGGL(merged_main<0>, dim3(256), dim3(512), 0, stream,
                       qpts, qtimes, dyn, (const __fp16*)nullptr, hbuf,
                       Wq, bq, Wk, bk, Wv, bv, Wo, bo, ws, out, M);
  }
}

// Round 18
// 912.944 us; speedup vs baseline: 1.6775x; 1.1488x over previous
//
#include <hip/hip_runtime.h>
#include <math.h>

#define M_D   120
#define MOD_T 201
#define TABLE_MASK 0xFFFFFu
#define INV_S 0.25819888974716115f   // 1/sqrt(15)

// ws float-region: S11[201*8] @0 ; TV'[201*128] @1608 ; TQK'[201*128] (u32) @27336
// frag dwords @53248 (byte 212992, 131072 B) ; TVh f16 @byte 344064 (51456 B)
// dyn16 @ 1 MB ; feat after dyn16
#define WS_TV   1608
#define WS_TQK  27336
#define WS_QF   53248
#define WS_TVH_BYTE 344064ull
#define WS_DYN16_BYTE (1ull << 20)

typedef float    f32x4 __attribute__((ext_vector_type(4)));
typedef uint32_t u32x4 __attribute__((ext_vector_type(4)));
typedef __fp16   f16x2v __attribute__((ext_vector_type(2)));
typedef __fp16   f16x4v __attribute__((ext_vector_type(4)));
typedef __fp16   f16x8 __attribute__((ext_vector_type(8)));

union PK2 { f16x2v h; uint32_t u; };
union BFrag { f16x8 v; f16x2v h2[4]; uint32_t u[4]; };

// ---------- precompute padded time-token tables (+ f16 TV copy) ----------
__global__ void precomp_time(const float* __restrict__ temb,
                             const float* __restrict__ Wq, const float* __restrict__ bq,
                             const float* __restrict__ Wk, const float* __restrict__ bk,
                             const float* __restrict__ Wv, const float* __restrict__ bv,
                             float* __restrict__ ws) {
  const int t = blockIdx.x, np = threadIdx.x;
  const int h = np >> 4, m = np & 15;
  const bool valid = (m < 15);
  const int col = h * 15 + m;
  __shared__ float lq[128], lk[128];
  float q = 0.f, k = 0.f, v = 0.f;
  if (valid) {
    q = bq[col]; k = bk[col]; v = bv[col];
    const float* te = temb + t * M_D;
    for (int i = 0; i < M_D; ++i) {
      float x = te[i];
      q = fmaf(x, Wq[i * M_D + col], q);
      k = fmaf(x, Wk[i * M_D + col], k);
      v = fmaf(x, Wv[i * M_D + col], v);
    }
  }
  lq[np] = q; lk[np] = k;
  ws[WS_TV + t * 128 + np] = v;
  ((__fp16*)((char*)ws + WS_TVH_BYTE))[t * 128 + np] = (__fp16)v;
  PK2 pk; pk.h[0] = (__fp16)(q * INV_S); pk.h[1] = (__fp16)k;
  ((uint32_t*)ws)[WS_TQK + t * 128 + np] = pk.u;
  __syncthreads();
  if (np < 8) {
    float s = 0.f;
    #pragma unroll
    for (int mm = 0; mm < 15; ++mm) s += lq[np * 16 + mm] * lk[np * 16 + mm];
    ws[t * 8 + np] = s * INV_S;
  }
}

// ---------- pack all 4 weight matrices into A-fragment order (f16) ----------
__global__ void pack_frags(const float* __restrict__ Wq, const float* __restrict__ bq,
                           const float* __restrict__ Wk, const float* __restrict__ bk,
                           const float* __restrict__ Wv, const float* __restrict__ bv,
                           const float* __restrict__ Wo, const float* __restrict__ bo,
                           float* __restrict__ ws) {
  const int idx = blockIdx.x * 1024 + threadIdx.x;   // 32 x 1024 = 32768
  const int mat = idx >> 13, r = idx & 8191;
  const int nt = r >> 10, kk = (r >> 8) & 3, l = (r >> 2) & 63, d = r & 3;
  const int mm = l & 15;
  const int i0 = kk * 32 + ((l >> 4) << 3) + 2 * d;
  float v0 = 0.f, v1 = 0.f;
  if (mat < 3) {
    const float* W = (mat == 0) ? Wq : (mat == 1) ? Wk : Wv;
    const float* b = (mat == 0) ? bq : (mat == 1) ? bk : bv;
    if (mm < 15) {
      const int col = nt * 15 + mm;
      const int ia = i0, ib = i0 + 1;
      v0 = (ia < 120) ? W[ia * M_D + col] : (ia == 120 ? b[col] : 0.f);
      v1 = (ib < 120) ? W[ib * M_D + col] : (ib == 120 ? b[col] : 0.f);
      if (mat == 0) { v0 *= INV_S; v1 *= INV_S; }
    }
  } else {
    const int n = nt * 16 + mm;
    if (n < M_D) {
      #pragma unroll
      for (int e = 0; e < 2; ++e) {
        const int ip = i0 + e;
        const int hi = ip >> 4, mi = ip & 15;
        float vv = 0.f;
        if (mi < 15) vv = Wo[(hi * 15 + mi) * M_D + n];
        else if (ip == 15) vv = bo[n];
        if (e == 0) v0 = vv; else v1 = vv;
      }
    }
  }
  PK2 pk; pk.h[0] = (__fp16)v0; pk.h[1] = (__fp16)v1;
  ((uint32_t*)ws)[WS_QF + idx] = pk.u;
}

// ---------- dyn f32 -> f16 table, 256B rows, pad halves zeroed ----------
__global__ void cvt_dyn(const float* __restrict__ dyn, __fp16* __restrict__ d16, int rows) {
  const int i = blockIdx.x * 256 + threadIdx.x;
  const int row = i >> 4, sub = i & 15;
  if (row < rows) {
    BFrag o;
    if (sub == 15) { o.u[0] = 0; o.u[1] = 0; o.u[2] = 0; o.u[3] = 0; }
    else {
      const float* src = dyn + (long)row * M_D + sub * 8;
      const f32x4 a = __builtin_nontemporal_load((const f32x4*)src);
      const f32x4 b = __builtin_nontemporal_load((const f32x4*)(src + 4));
      o.h2[0] = __builtin_amdgcn_cvt_pkrtz(a[0], a[1]);
      o.h2[1] = __builtin_amdgcn_cvt_pkrtz(a[2], a[3]);
      o.h2[2] = __builtin_amdgcn_cvt_pkrtz(b[0], b[1]);
      o.h2[3] = __builtin_amdgcn_cvt_pkrtz(b[2], b[3]);
    }
    *(f16x8*)(d16 + (long)row * 128 + sub * 8) = o.v;
  }
}

// ---------- stage 1: hash + deep-burst gather -> interpolated f16 rows ----------
__launch_bounds__(256, 2)
__global__ void gather_feat(const float* __restrict__ qpts, const __fp16* __restrict__ dyn16,
                            const int* __restrict__ hbuf, __fp16* __restrict__ feat, int M) {
  const int l = threadIdx.x & 63, wv = threadIdx.x >> 6;
  const int g = l >> 4, pl = l & 15;
  const int T = (M + 15) >> 4;
  for (int tile = blockIdx.x * 4 + wv; tile < T; tile += gridDim.x * 4) {
    const int pid = (tile << 4) + pl;
    const int p = (pid < M) ? pid : (M - 1);
    const float px = qpts[3 * p], py = qpts[3 * p + 1], pz = qpts[3 * p + 2];
    const float gx = px / 0.1f, gy = py / 0.1f, gz = pz / 0.1f;
    const float fx = floorf(gx), fy = floorf(gy), fz = floorf(gz);
    const float rx = gx - fx, ry = gy - fy, rz = gz - fz;
    const int bx = (int)fx, by = (int)fy, bz = (int)fz;

    int voff[8]; float wcv[8];
    #pragma unroll
    for (int c = 0; c < 8; ++c) {
      const int ox = c & 1, oy = (c >> 1) & 1, oz = c >> 2;
      const uint32_t hh = (uint32_t)(bx + ox) * 73856093u +
                          (uint32_t)(by + oy) * 19349669u +
                          (uint32_t)(bz + oz) * 83492791u;
      const int vc = hbuf[hh & TABLE_MASK];
      const float wc = (ox ? rx : 1.f - rx) * (oy ? ry : 1.f - ry) * (oz ? rz : 1.f - rz);
      wcv[c] = (vc >= 0) ? wc : 0.f;
      voff[c] = ((vc >= 0) ? vc : 0) * 128 + g * 8;
    }

    __fp16* frow = feat + (long)pid * 128 + g * 8;
    f16x8 va[8], vb[8];
    #pragma unroll
    for (int c = 0; c < 8; ++c) va[c] = *(const f16x8*)(dyn16 + voff[c]);
    #pragma unroll
    for (int c = 0; c < 8; ++c) vb[c] = *(const f16x8*)(dyn16 + voff[c] + 32);

    auto PROC = [&](int kk, f16x8* vk) {
      f32x4 accA = {0, 0, 0, 0}, accB = {0, 0, 0, 0};
      #pragma unroll
      for (int c = 0; c < 8; ++c) {
        const float wc = wcv[c];
        const f16x8 v8 = vk[c];
        accA[0] = fmaf((float)v8[0], wc, accA[0]);
        accA[1] = fmaf((float)v8[1], wc, accA[1]);
        accA[2] = fmaf((float)v8[2], wc, accA[2]);
        accA[3] = fmaf((float)v8[3], wc, accA[3]);
        accB[0] = fmaf((float)v8[4], wc, accB[0]);
        accB[1] = fmaf((float)v8[5], wc, accB[1]);
        accB[2] = fmaf((float)v8[6], wc, accB[2]);
        accB[3] = fmaf((float)v8[7], wc, accB[3]);
      }
      if (kk == 3 && g == 3) accA[0] = 1.0f;   // bias slot k=120 (pads are zero)
      BFrag o;
      o.h2[0] = __builtin_amdgcn_cvt_pkrtz(accA[0], accA[1]);
      o.h2[1] = __builtin_amdgcn_cvt_pkrtz(accA[2], accA[3]);
      o.h2[2] = __builtin_amdgcn_cvt_pkrtz(accB[0], accB[1]);
      o.h2[3] = __builtin_amdgcn_cvt_pkrtz(accB[2], accB[3]);
      if (pid < M) __builtin_nontemporal_store(o.v, (f16x8*)(frow + kk * 32));
    };

    PROC(0, va);
    #pragma unroll
    for (int c = 0; c < 8; ++c) va[c] = *(const f16x8*)(dyn16 + voff[c] + 64);
    PROC(1, vb);
    #pragma unroll
    for (int c = 0; c < 8; ++c) vb[c] = *(const f16x8*)(dyn16 + voff[c] + 96);
    PROC(2, va);
    PROC(3, vb);
  }
}

// ---------- stage 2: MFMA attention — NO LDS; hot sets L2-resident via NT streams ----------
__launch_bounds__(512, 2)
__global__ void mfma_main(const int* __restrict__ qtimes, const __fp16* __restrict__ feat,
                          const float* __restrict__ ws, float* __restrict__ out, int M) {
  const uint32_t* wqg = (const uint32_t*)ws + WS_QF;   // frag streams (L2-resident)
  const uint32_t* wkg = wqg + 8192;
  const uint32_t* wvg = wqg + 16384;
  const uint32_t* wog = wqg + 24576;
  const uint32_t* TQK = (const uint32_t*)ws + WS_TQK;  // time tables (L2-resident)
  const __fp16*   TVh = (const __fp16*)((const char*)ws + WS_TVH_BYTE);
  const float*    S11 = ws;

  const int tid = threadIdx.x;
  const int l = tid & 63, wv = tid >> 6;
  const int g = l >> 4, pl = l & 15, c0 = g << 2;

  const int T = (M + 15) >> 4;
  for (int tile = blockIdx.x * 8 + wv; tile < T; tile += gridDim.x * 8) {
    const int pid = (tile << 4) + pl;
    const bool valid = (pid < M);
    const int p = valid ? pid : (M - 1);
    const int tm = qtimes[p] % MOD_T;

    // ---- sequential fragment loads (stage-1 output), NON-TEMPORAL ----
    BFrag bf[4];
    const __fp16* frow = feat + (long)p * 128 + g * 8;
    #pragma unroll
    for (int kk = 0; kk < 4; ++kk)
      bf[kk].v = __builtin_nontemporal_load((const f16x8*)(frow + kk * 32));

    // ---- time-token data (random tm -> small L2-resident tables) ----
    f32x4 tvv[8]; u32x4 tqk[8]; float s11v[8];
    #pragma unroll
    for (int nt = 0; nt < 8; ++nt) {
      const f16x4v th = *(const f16x4v*)(TVh + tm * 128 + nt * 16 + c0);
      tvv[nt][0] = (float)th[0]; tvv[nt][1] = (float)th[1];
      tvv[nt][2] = (float)th[2]; tvv[nt][3] = (float)th[3];
      tqk[nt] = *(const u32x4*)(TQK + tm * 128 + nt * 16 + c0);
      s11v[nt] = S11[tm * 8 + nt];
    }

    f32x4 aq[8], ak[8], av[8];
    #pragma unroll
    for (int nt = 0; nt < 8; ++nt) {
      f32x4 zq = {0,0,0,0}, zk = {0,0,0,0}, zv = {0,0,0,0};
      #pragma unroll
      for (int kk = 0; kk < 4; ++kk) {
        const int off = nt * 1024 + kk * 256 + l * 4;
        f16x8 a0 = *(const f16x8*)(wqg + off);
        f16x8 a1 = *(const f16x8*)(wkg + off);
        f16x8 a2 = *(const f16x8*)(wvg + off);
        zq = __builtin_amdgcn_mfma_f32_16x16x32_f16(a0, bf[kk].v, zq, 0, 0, 0);
        zk = __builtin_amdgcn_mfma_f32_16x16x32_f16(a1, bf[kk].v, zk, 0, 0, 0);
        zv = __builtin_amdgcn_mfma_f32_16x16x32_f16(a2, bf[kk].v, zv, 0, 0, 0);
      }
      aq[nt] = zq; ak[nt] = zk; av[nt] = zv;
    }

    float a_[8], b_[8];
    #pragma unroll
    for (int nt = 0; nt < 8; ++nt) {
      float s00 = 0.f, s01 = 0.f, s10 = 0.f;
      #pragma unroll
      for (int r = 0; r < 4; ++r) {
        const float qv = aq[nt][r], kv = ak[nt][r];
        PK2 tt; tt.u = tqk[nt][r];
        const float tqs = (float)tt.h[0], tk = (float)tt.h[1];
        s00 = fmaf(qv, kv, s00);
        s01 = fmaf(qv, tk, s01);
        s10 = fmaf(tqs, kv, s10);
      }
      s00 += __shfl_xor(s00, 16); s00 += __shfl_xor(s00, 32);
      s01 += __shfl_xor(s01, 16); s01 += __shfl_xor(s01, 32);
      s10 += __shfl_xor(s10, 16); s10 += __shfl_xor(s10, 32);
      const float s11 = s11v[nt];
      const float m0 = fmaxf(s00, s01), m1 = fmaxf(s10, s11);
      const float e00 = __expf(s00 - m0), e01 = __expf(s01 - m0);
      const float e10 = __expf(s10 - m1), e11 = __expf(s11 - m1);
      const float r0 = 1.f / (e00 + e01), r1 = 1.f / (e10 + e11);
      a_[nt] = 0.5f * (e00 * r0 + e10 * r1);
      b_[nt] = 0.5f * (e01 * r0 + e11 * r1);
    }

    uint32_t cdw[8][2];
    #pragma unroll
    for (int nt = 0; nt < 8; ++nt) {
      f32x4 cv;
      #pragma unroll
      for (int r = 0; r < 4; ++r) cv[r] = a_[nt] * av[nt][r] + b_[nt] * tvv[nt][r];
      if (nt == 0 && g == 3) cv[3] = 1.0f;
      PK2 p0, p1;
      p0.h = __builtin_amdgcn_cvt_pkrtz(cv[0], cv[1]);
      p1.h = __builtin_amdgcn_cvt_pkrtz(cv[2], cv[3]);
      cdw[nt][0] = p0.u; cdw[nt][1] = p1.u;
    }

    const int src0 = pl | ((g & 1) << 5);
    const int src1 = src0 + 16;
    const bool hsel = (g >= 2);
    BFrag bco[4];
    #pragma unroll
    for (int kk = 0; kk < 4; ++kk) {
      #pragma unroll
      for (int d = 0; d < 4; ++d) {
        const int s = (d >= 2) ? src1 : src0;
        const int vlo = __shfl((int)cdw[2 * kk][d & 1], s, 64);
        const int vhi = __shfl((int)cdw[2 * kk + 1][d & 1], s, 64);
        bco[kk].u[d] = hsel ? (uint32_t)vhi : (uint32_t)vlo;
      }
    }

    float* orow = out + (long)p * M_D;
    #pragma unroll
    for (int nt = 0; nt < 8; ++nt) {
      f32x4 zo = {0,0,0,0};
      #pragma unroll
      for (int kk = 0; kk < 4; ++kk) {
        f16x8 a3 = *(const f16x8*)(wog + nt * 1024 + kk * 256 + l * 4);
        zo = __builtin_amdgcn_mfma_f32_16x16x32_f16(a3, bco[kk].v, zo, 0, 0, 0);
      }
      if (valid && (nt < 7 || g < 2))
        __builtin_nontemporal_store(zo, (f32x4*)(orow + nt * 16 + c0));
    }
  }
}

// ---------- fallback: merged kernel (round-9 structure, padded f16 table) ----------
template <int USE16>
__launch_bounds__(512, 2)
__global__ void merged_main(const float* __restrict__ qpts, const int* __restrict__ qtimes,
                            const float* __restrict__ dyn,  const __fp16* __restrict__ dyn16,
                            const int* __restrict__ hbuf,
                            const float* __restrict__ Wq, const float* __restrict__ bq,
                            const float* __restrict__ Wk, const float* __restrict__ bk,
                            const float* __restrict__ Wv, const float* __restrict__ bv,
                            const float* __restrict__ Wo, const float* __restrict__ bo,
                            const float* __restrict__ ws, float* __restrict__ out, int M) {
  __shared__ __align__(16) uint32_t wlds[4 * 8192];
  const int tid = threadIdx.x;
  for (int idx = tid; idx < 32768; idx += 512) {
    const int mat = idx >> 13, r = idx & 8191;
    const int nt = r >> 10, kk = (r >> 8) & 3, l = (r >> 2) & 63, d = r & 3;
    const int mm = l & 15;
    const int i0 = kk * 32 + ((l >> 4) << 3) + 2 * d;
    float v0 = 0.f, v1 = 0.f;
    if (mat < 3) {
      const float* W = (mat == 0) ? Wq : (mat == 1) ? Wk : Wv;
      const float* b = (mat == 0) ? bq : (mat == 1) ? bk : bv;
      if (mm < 15) {
        const int col = nt * 15 + mm;
        const int ia = i0, ib = i0 + 1;
        v0 = (ia < 120) ? W[ia * M_D + col] : (ia == 120 ? b[col] : 0.f);
        v1 = (ib < 120) ? W[ib * M_D + col] : (ib == 120 ? b[col] : 0.f);
        if (mat == 0) { v0 *= INV_S; v1 *= INV_S; }
      }
    } else {
      const int n = nt * 16 + mm;
      if (n < M_D) {
        #pragma unroll
        for (int e = 0; e < 2; ++e) {
          const int ip = i0 + e;
          const int hi = ip >> 4, mi = ip & 15;
          float vv = 0.f;
          if (mi < 15) vv = Wo[(hi * 15 + mi) * M_D + n];
          else if (ip == 15) vv = bo[n];
          if (e == 0) v0 = vv; else v1 = vv;
        }
      }
    }
    PK2 pk; pk.h[0] = (__fp16)v0; pk.h[1] = (__fp16)v1;
    wlds[idx] = pk.u;
  }
  __syncthreads();

  const uint32_t* wq = wlds;
  const uint32_t* wk = wlds + 8192;
  const uint32_t* wvm = wlds + 2 * 8192;
  const uint32_t* wo = wlds + 3 * 8192;
  const int l = tid & 63, wv = tid >> 6;
  const int g = l >> 4, pl = l & 15, c0 = g << 2;
  const float* S11 = ws;
  const float* TVt = ws + WS_TV;
  const uint32_t* TQK = (const uint32_t*)ws + WS_TQK;

  const int T = (M + 15) >> 4;
  for (int tile = blockIdx.x * 8 + wv; tile < T; tile += gridDim.x * 8) {
    const int pid = (tile << 4) + pl;
    const int p = (pid < M) ? pid : (M - 1);
    const float px = qpts[3 * p], py = qpts[3 * p + 1], pz = qpts[3 * p + 2];
    const int tm = qtimes[p] % MOD_T;
    const float gx = px / 0.1f, gy = py / 0.1f, gz = pz / 0.1f;
    const float fx = floorf(gx), fy = floorf(gy), fz = floorf(gz);
    const float rx = gx - fx, ry = gy - fy, rz = gz - fz;
    const int bx = (int)fx, by = (int)fy, bz = (int)fz;
    const int i0g = g * 8;
    int voff[8]; float wcv[8];
    #pragma unroll
    for (int c = 0; c < 8; ++c) {
      const int ox = c & 1, oy = (c >> 1) & 1, oz = c >> 2;
      const uint32_t hh = (uint32_t)(bx + ox) * 73856093u +
                          (uint32_t)(by + oy) * 19349669u +
                          (uint32_t)(bz + oz) * 83492791u;
      const int vc = hbuf[hh & TABLE_MASK];
      const float wc = (ox ? rx : 1.f - rx) * (oy ? ry : 1.f - ry) * (oz ? rz : 1.f - rz);
      wcv[c] = (vc >= 0) ? wc : 0.f;
      const int vr = (vc >= 0) ? vc : 0;
      voff[c] = (USE16 ? vr * 128 : vr * M_D) + i0g;
    }
    BFrag bf[4];
    #pragma unroll
    for (int kk = 0; kk < 4; ++kk) {
      f32x4 accA = {0, 0, 0, 0}, accB = {0, 0, 0, 0};
      if (kk < 3 || g < 3) {
        #pragma unroll
        for (int c = 0; c < 8; ++c) {
          const float wc = wcv[c];
          if (USE16) {
            const f16x8 v8 = *(const f16x8*)(dyn16 + voff[c] + kk * 32);
            accA[0] = fmaf((float)v8[0], wc, accA[0]);
            accA[1] = fmaf((float)v8[1], wc, accA[1]);
            accA[2] = fmaf((float)v8[2], wc, accA[2]);
            accA[3] = fmaf((float)v8[3], wc, accA[3]);
            accB[0] = fmaf((float)v8[4], wc, accB[0]);
            accB[1] = fmaf((float)v8[5], wc, accB[1]);
            accB[2] = fmaf((float)v8[6], wc, accB[2]);
            accB[3] = fmaf((float)v8[7], wc, accB[3]);
          } else {
            const float* fr = dyn + voff[c];
            f32x4 lo4 = *(const f32x4*)(fr + kk * 32);
            f32x4 hi4 = *(const f32x4*)(fr + kk * 32 + 4);
            accA += lo4 * wc;
            accB += hi4 * wc;
          }
        }
      }
      if (kk == 3 && g == 3) accA[0] = 1.0f;
      bf[kk].h2[0] = __builtin_amdgcn_cvt_pkrtz(accA[0], accA[1]);
      bf[kk].h2[1] = __builtin_amdgcn_cvt_pkrtz(accA[2], accA[3]);
      bf[kk].h2[2] = __builtin_amdgcn_cvt_pkrtz(accB[0], accB[1]);
      bf[kk].h2[3] = __builtin_amdgcn_cvt_pkrtz(accB[2], accB[3]);
    }
    f32x4 tvv[8]; u32x4 tqk[8]; float s11v[8];
    #pragma unroll
    for (int nt = 0; nt < 8; ++nt) {
      tvv[nt] = *(const f32x4*)(TVt + tm * 128 + nt * 16 + c0);
      tqk[nt] = *(const u32x4*)(TQK + tm * 128 + nt * 16 + c0);
      s11v[nt] = S11[tm * 8 + nt];
    }
    f32x4 aq[8], ak[8], av[8];
    #pragma unroll
    for (int nt = 0; nt < 8; ++nt) {
      f32x4 zq = {0,0,0,0}, zk = {0,0,0,0}, zv = {0,0,0,0};
      #pragma unroll
      for (int kk = 0; kk < 4; ++kk) {
        const int off = nt * 1024 + kk * 256 + l * 4;
        f16x8 a0 = *(const f16x8*)(wq + off);
        f16x8 a1 = *(const f16x8*)(wk + off);
        f16x8 a2 = *(const f16x8*)(wvm + off);
        zq = __builtin_amdgcn_mfma_f32_16x16x32_f16(a0, bf[kk].v, zq, 0, 0, 0);
        zk = __builtin_amdgcn_mfma_f32_16x16x32_f16(a1, bf[kk].v, zk, 0, 0, 0);
        zv = __builtin_amdgcn_mfma_f32_16x16x32_f16(a2, bf[kk].v, zv, 0, 0, 0);
      }
      aq[nt] = zq; ak[nt] = zk; av[nt] = zv;
    }
    float a_[8], b_[8];
    #pragma unroll
    for (int nt = 0; nt < 8; ++nt) {
      float s00 = 0.f, s01 = 0.f, s10 = 0.f;
      #pragma unroll
      for (int r = 0; r < 4; ++r) {
        const float qv = aq[nt][r], kv = ak[nt][r];
        PK2 tt; tt.u = tqk[nt][r];
        s00 = fmaf(qv, kv, s00);
        s01 = fmaf(qv, (float)tt.h[1], s01);
        s10 = fmaf((float)tt.h[0], kv, s10);
      }
      s00 += __shfl_xor(s00, 16); s00 += __shfl_xor(s00, 32);
      s01 += __shfl_xor(s01, 16); s01 += __shfl_xor(s01, 32);
      s10 += __shfl_xor(s10, 16); s10 += __shfl_xor(s10, 32);
      const float s11 = s11v[nt];
      const float m0 = fmaxf(s00, s01), m1 = fmaxf(s10, s11);
      const float e00 = __expf(s00 - m0), e01 = __expf(s01 - m0);
      const float e10 = __expf(s10 - m1), e11 = __expf(s11 - m1);
      const float r0 = 1.f / (e00 + e01), r1 = 1.f / (e10 + e11);
      a_[nt] = 0.5f * (e00 * r0 + e10 * r1);
      b_[nt] = 0.5f * (e01 * r0 + e11 * r1);
    }
    uint32_t cdw[8][2];
    #pragma unroll
    for (int nt = 0; nt < 8; ++nt) {
      f32x4 cv;
      #pragma unroll
      for (int r = 0; r < 4; ++r) cv[r] = a_[nt] * av[nt][r] + b_[nt] * tvv[nt][r];
      if (nt == 0 && g == 3) cv[3] = 1.0f;
      PK2 p0, p1;
      p0.h = __builtin_amdgcn_cvt_pkrtz(cv[0], cv[1]);
      p1.h = __builtin_amdgcn_cvt_pkrtz(cv[2], cv[3]);
      cdw[nt][0] = p0.u; cdw[nt][1] = p1.u;
    }
    const int src0 = pl | ((g & 1) << 5);
    const int src1 = src0 + 16;
    const bool hsel = (g >= 2);
    BFrag bco[4];
    #pragma unroll
    for (int kk = 0; kk < 4; ++kk) {
      #pragma unroll
      for (int d = 0; d < 4; ++d) {
        const int s = (d >= 2) ? src1 : src0;
        const int vlo = __shfl((int)cdw[2 * kk][d & 1], s, 64);
        const int vhi = __shfl((int)cdw[2 * kk + 1][d & 1], s, 64);
        bco[kk].u[d] = hsel ? (uint32_t)vhi : (uint32_t)vlo;
      }
    }
    float* orow = out + (long)pid * M_D;
    #pragma unroll
    for (int nt = 0; nt < 8; ++nt) {
      f32x4 zo = {0,0,0,0};
      #pragma unroll
      for (int kk = 0; kk < 4; ++kk) {
        f16x8 a3 = *(const f16x8*)(wo + nt * 1024 + kk * 256 + l * 4);
        zo = __builtin_amdgcn_mfma_f32_16x16x32_f16(a3, bco[kk].v, zo, 0, 0, 0);
      }
      if (pid < M && (nt < 7 || g < 2))
        *(f32x4*)(orow + nt * 16 + c0) = zo;
    }
  }
}

extern "C" void kernel_launch(void* const* d_in, const int* in_sizes, int n_in,
                              void* d_out, int out_size, void* d_ws, size_t ws_size,
                              hipStream_t stream) {
  const float* qpts   = (const float*)d_in[0];
  const int*   qtimes = (const int*)d_in[1];
  const float* dyn    = (const float*)d_in[2];
  const float* temb   = (const float*)d_in[3];
  const int*   hbuf   = (const int*)d_in[4];
  const float* Wq = (const float*)d_in[5];
  const float* bq = (const float*)d_in[6];
  const float* Wk = (const float*)d_in[7];
  const float* bk = (const float*)d_in[8];
  const float* Wv = (const float*)d_in[9];
  const float* bv = (const float*)d_in[10];
  const float* Wo = (const float*)d_in[11];
  const float* bo = (const float*)d_in[12];
  float* out = (float*)d_out;
  float* ws  = (float*)d_ws;
  const int M = in_sizes[1];
  const int ndyn = in_sizes[2];
  const int rows = ndyn / M_D;

  hipLaunchKernelGGL(precomp_time, dim3(MOD_T), dim3(128), 0, stream,
                     temb, Wq, bq, Wk, bk, Wv, bv, ws);

  const size_t dyn16_bytes = (size_t)rows * 256;
  const size_t need16 = WS_DYN16_BYTE + dyn16_bytes;
  const size_t feat_off = (need16 + 255) & ~255ull;
  const size_t T16 = (size_t)(((M + 15) / 16) * 16);
  const size_t needF = feat_off + T16 * 256;

  if (ws_size >= need16) {
    __fp16* d16 = (__fp16*)((char*)d_ws + WS_DYN16_BYTE);
    const int nchunk = rows * 16;
    hipLaunchKernelGGL(cvt_dyn, dim3((nchunk + 255) / 256), dim3(256), 0, stream,
                       dyn, d16, rows);
    if (ws_size >= needF) {
      __fp16* feat = (__fp16*)((char*)d_ws + feat_off);
      hipLaunchKernelGGL(pack_frags, dim3(32), dim3(1024), 0, stream,
                         Wq, bq, Wk, bk, Wv, bv, Wo, bo, ws);
      hipLaunchKernelGGL(gather_feat, dim3(2048), dim3(256), 0, stream,
                         qpts, d16, hbuf, feat, M);
      hipLaunchKernelGGL(mfma_main, dim3(512), dim3(512), 0, stream,
                         qtimes, feat, ws, out, M);
    } else {
      hipLaunchKernelGGL(merged_main<1>, dim3(256), dim3(512), 0, stream,
                         qpts, qtimes, dyn, d16, hbuf,
                         Wq, bq, Wk, bk, Wv, bv, Wo, bo, ws, out, M);
    }
  } else {
    hipLaunchKernelGGL(merged_main<0>, dim3(256), dim3(512), 0, stream,
                       qpts, qtimes, dyn, (const __fp16*)nullptr, hbuf,
                       Wq, bq, Wk, bk, Wv, bv, Wo, bo, ws, out, M);
  }
}